// Round 10
// baseline (154.115 us; speedup 1.0000x reference)
//
#include <hip/hip_runtime.h>
#include <hip/hip_cooperative_groups.h>
#include <math.h>
#include <stdint.h>

namespace cg = cooperative_groups;

// Problem constants (from reference): B=32, A=3, S=52, C=80
constexpr int NCELL = 32 * 3 * 52 * 52;   // 259584 = 256 * 1014
constexpr int PS = 85;                    // prediction channels (5 + C)
constexpr int TPB = 256;
constexpr int NBLK = NCELL / TPB;         // 1014 (<= 4 blocks/CU * 256 CU co-resident)

// d_ws: per-block partials, 8 floats (32 B) per block; NBLK slots (32,448 B).
// [b*8 + 0..5] = {bce_noobj, n_noobj, obj_term, n_obj, box_se, nll}

__global__ __launch_bounds__(TPB, 4) void yolo_fused(const float* __restrict__ pred,
                                                     const float* __restrict__ tgt,
                                                     float* __restrict__ part,
                                                     float* __restrict__ out)
{
    const int tid  = threadIdx.x;
    const int wid  = tid >> 6;
    const int lane = tid & 63;
    const int cell = blockIdx.x * TPB + tid;            // one cell per thread

    __shared__ float red[4][6];

    // ---- always: first aligned float4 of the pred window (contains p0) ----
    // 85c mod 4 == c mod 4; window [85c & ~3, +4) always holds dword 85c.
    const int pi = (cell * PS) >> 2;
    const float4* pa = (const float4*)pred;
    float4 A = pa[pi];
    const int o = cell & 3;
    float p0 = o==0 ? A.x : o==1 ? A.y : o==2 ? A.z : A.w;

    // ---- always: first aligned float4 of the tgt window (contains t0) ----
    // 6c mod 4 = 2*(c&1); t0 = TA.x (even c) or TA.z (odd c).
    const int ti = (cell * 6) >> 2;
    const float4* pt = (const float4*)tgt;
    float4 TA = pt[ti];
    const bool oh = (cell & 1);
    float t0 = oh ? TA.z : TA.x;

    const bool obj   = (t0 == 1.0f);
    const bool noobj = (t0 == 0.0f);

    float s0=0.f, s1=0.f, s2=0.f, s3=0.f, s4=0.f, s5=0.f;
    float t5 = 0.0f;    // label; only meaningful on obj lanes (shfl-read later)

    // BCE-with-logits on objectness (uses only p0, t0)
    float bce = fmaxf(p0, 0.0f) - p0 * t0 + log1pf(__expf(-fabsf(p0)));
    if (noobj) { s0 = bce; s1 = 1.0f; }

    // ---- obj-only (≈5% of lanes): second float4s + box/IoU/obj terms ----
    if (obj) {
        float4 Bv = pa[pi + 1];
        float4 TB = pt[ti + 1];

        float p1 = o==0 ? A.y  : o==1 ? A.z  : o==2 ? A.w  : Bv.x;
        float p2 = o==0 ? A.z  : o==1 ? A.w  : o==2 ? Bv.x : Bv.y;
        float p3 = o==0 ? A.w  : o==1 ? Bv.x : o==2 ? Bv.y : Bv.z;
        float p4 = o==0 ? Bv.x : o==1 ? Bv.y : o==2 ? Bv.z : Bv.w;

        float t1 = oh ? TA.w : TA.y;
        float t2 = oh ? TB.x : TA.z;
        float t3 = oh ? TB.y : TA.w;
        float t4 = oh ? TB.z : TB.x;
        t5       = oh ? TB.w : TB.y;

        // midpoint IoU: b1 = pred[0:4], b2 = target[1:5]
        float b1x1 = p0 - p2 * 0.5f, b1y1 = p1 - p3 * 0.5f;
        float b1x2 = p0 + p2 * 0.5f, b1y2 = p1 + p3 * 0.5f;
        float b2x1 = t1 - t3 * 0.5f, b2y1 = t2 - t4 * 0.5f;
        float b2x2 = t1 + t3 * 0.5f, b2y2 = t2 + t4 * 0.5f;
        float xi1 = fmaxf(b1x1, b2x1), yi1 = fmaxf(b1y1, b2y1);
        float xi2 = fminf(b1x2, b2x2), yi2 = fminf(b1y2, b2y2);
        float inter = fmaxf(xi2 - xi1, 0.0f) * fmaxf(yi2 - yi1, 0.0f);
        float a1 = fabsf((b1x2 - b1x1) * (b1y2 - b1y1));
        float a2 = fabsf((b2x2 - b2x1) * (b2y2 - b2y1));
        float iou = inter / (a1 + a2 - inter + 1e-6f);

        float pobj = 1.0f / (1.0f + __expf(-p0));
        float dob  = pobj - iou;            // t0 == 1 here

        float d1 = 1.0f / (1.0f + __expf(-p1)) - t1;
        float d2 = 1.0f / (1.0f + __expf(-p2)) - t2;
        float d3 = 1.0f / (1.0f + __expf(-p3)) - t3;
        float d4 = 1.0f / (1.0f + __expf(-p4)) - t4;

        s2 = dob * dob;
        s4 = d1*d1 + d2*d2 + d3*d3 + d4*d4;
    }

    // ---- wave-cooperative softmax for obj cells only ----
    unsigned long long mask = __ballot(obj);
    if (lane == 0) s3 = (float)__popcll(mask);          // n_obj for this wave

    const int waveCell0 = blockIdx.x * TPB + wid * 64;
    while (mask) {
        int L = __builtin_ctzll(mask);                  // wave-uniform owner lane
        mask &= mask - 1;

        const float* row = pred + (size_t)(waveCell0 + L) * PS;
        // 80 logits: lanes 0..63 read class=lane, lanes 0..15 also class=64+lane
        float v0 = row[5 + lane];
        float v1 = (lane < 16) ? row[69 + lane] : -INFINITY;

        float m = fmaxf(v0, v1);
        #pragma unroll
        for (int off = 1; off < 64; off <<= 1)
            m = fmaxf(m, __shfl_xor(m, off));

        float e = __expf(v0 - m) + ((lane < 16) ? __expf(v1 - m) : 0.0f);
        #pragma unroll
        for (int off = 1; off < 64; off <<= 1)
            e += __shfl_xor(e, off);

        int lbl = (int)__shfl(t5, L);
        float sel = (lbl < 64) ? __shfl(v0, lbl) : __shfl(v1, lbl - 64);

        if (lane == 0) s5 += __logf(e) - (sel - m);
    }

    // ---- wave butterfly reduction of the 6 partials ----
    #pragma unroll
    for (int off = 1; off < 64; off <<= 1) {
        s0 += __shfl_xor(s0, off);
        s1 += __shfl_xor(s1, off);
        s2 += __shfl_xor(s2, off);
        s3 += __shfl_xor(s3, off);
        s4 += __shfl_xor(s4, off);
        s5 += __shfl_xor(s5, off);
    }

    // ---- cross-wave reduction (4 waves), one float4-pair store per block ----
    if (lane == 0) {
        red[wid][0] = s0; red[wid][1] = s1; red[wid][2] = s2;
        red[wid][3] = s3; red[wid][4] = s4; red[wid][5] = s5;
    }
    __syncthreads();
    if (tid == 0) {
        float a0=0.f,a1=0.f,a2=0.f,a3=0.f,a4=0.f,a5=0.f;
        #pragma unroll
        for (int w = 0; w < 4; ++w) {
            a0 += red[w][0]; a1 += red[w][1]; a2 += red[w][2];
            a3 += red[w][3]; a4 += red[w][4]; a5 += red[w][5];
        }
        float4* slot = (float4*)(part + (size_t)blockIdx.x * 8);
        slot[0] = make_float4(a0, a1, a2, a3);
        slot[1] = make_float4(a4, a5, 0.0f, 0.0f);
    }

    __threadfence();
    cg::this_grid().sync();

    // ---- block 0: final reduce over NBLK slots + loss computation ----
    if (blockIdx.x == 0) {
        float a0=0.f,a1=0.f,a2=0.f,a3=0.f,a4=0.f,a5=0.f;
        for (int i = tid; i < NBLK; i += TPB) {     // ≤ 4 slots per thread
            const float4* slot = (const float4*)(part + (size_t)i * 8);
            float4 v0 = slot[0];
            float4 v1 = slot[1];
            a0 += v0.x; a1 += v0.y; a2 += v0.z;
            a3 += v0.w; a4 += v1.x; a5 += v1.y;
        }
        #pragma unroll
        for (int off = 1; off < 64; off <<= 1) {
            a0 += __shfl_xor(a0, off);
            a1 += __shfl_xor(a1, off);
            a2 += __shfl_xor(a2, off);
            a3 += __shfl_xor(a3, off);
            a4 += __shfl_xor(a4, off);
            a5 += __shfl_xor(a5, off);
        }
        __syncthreads();   // red[] reuse
        if (lane == 0) {
            red[wid][0] = a0; red[wid][1] = a1; red[wid][2] = a2;
            red[wid][3] = a3; red[wid][4] = a4; red[wid][5] = a5;
        }
        __syncthreads();
        if (tid == 0) {
            float b0=0.f,b1=0.f,b2=0.f,b3=0.f,b4=0.f,b5=0.f;
            #pragma unroll
            for (int w = 0; w < 4; ++w) {
                b0 += red[w][0]; b1 += red[w][1]; b2 += red[w][2];
                b3 += red[w][3]; b4 += red[w][4]; b5 += red[w][5];
            }
            float n_noobj = b1;
            float n_obj   = b3;
            // return order: (5*box, 1*object, 0.5*noobj, 1*class)
            out[0] = 5.0f * b4 / fmaxf(n_obj * 4.0f, 1.0f);
            out[1] = 1.0f * b2 / fmaxf(n_obj, 1.0f);
            out[2] = 0.5f * b0 / fmaxf(n_noobj, 1.0f);
            out[3] = 1.0f * b5 / fmaxf(n_obj, 1.0f);
        }
    }
}

extern "C" void kernel_launch(void* const* d_in, const int* in_sizes, int n_in,
                              void* d_out, int out_size, void* d_ws, size_t ws_size,
                              hipStream_t stream)
{
    const float* pred = (const float*)d_in[0];
    const float* tgt  = (const float*)d_in[1];
    float* out  = (float*)d_out;
    float* part = (float*)d_ws;   // needs NBLK*8*4 = 32,448 B

    void* args[] = { (void*)&pred, (void*)&tgt, (void*)&part, (void*)&out };
    hipLaunchCooperativeKernel((void*)yolo_fused, dim3(NBLK), dim3(TPB),
                               args, 0, stream);
}

// Round 11
// 23.575 us; speedup vs baseline: 6.5373x; 6.5373x over previous
//
#include <hip/hip_runtime.h>
#include <math.h>
#include <stdint.h>

// Problem constants (from reference): B=32, A=3, S=52, C=80
constexpr int NCELL = 32 * 3 * 52 * 52;   // 259584 = 256 * 1014
constexpr int PS = 85;                    // prediction channels (5 + C)
constexpr int TPB = 256;
constexpr int NBLK = NCELL / TPB;         // 1014

// d_ws: per-block partials, 8 floats (32 B) per block; NBLK slots.
// [b*8 + 0..5] = {bce_noobj, n_noobj, obj_term, n_obj, box_se, nll}

__global__ __launch_bounds__(TPB) void yolo_main(const float* __restrict__ pred,
                                                 const float* __restrict__ tgt,
                                                 float* __restrict__ part)
{
    const int tid  = threadIdx.x;
    const int wid  = tid >> 6;
    const int lane = tid & 63;
    const int cell = blockIdx.x * TPB + tid;            // one cell per thread

    __shared__ float red[4][6];

    // ---- always: first aligned float4 of the pred window (contains p0) ----
    // 85c mod 4 == c mod 4; window [85c & ~3, +4) always holds dword 85c.
    const int pi = (cell * PS) >> 2;
    const float4* pa = (const float4*)pred;
    float4 A = pa[pi];
    const int o = cell & 3;
    float p0 = o==0 ? A.x : o==1 ? A.y : o==2 ? A.z : A.w;

    // ---- always: first aligned float4 of the tgt window (contains t0) ----
    // 6c mod 4 = 2*(c&1); t0 = TA.x (even c) or TA.z (odd c).
    const int ti = (cell * 6) >> 2;
    const float4* pt = (const float4*)tgt;
    float4 TA = pt[ti];
    const bool oh = (cell & 1);
    float t0 = oh ? TA.z : TA.x;

    const bool obj   = (t0 == 1.0f);
    const bool noobj = (t0 == 0.0f);

    float s0=0.f, s1=0.f, s2=0.f, s3=0.f, s4=0.f, s5=0.f;
    float t5 = 0.0f;    // label; meaningful only on obj lanes (shfl-read later)

    // BCE-with-logits on objectness (uses only p0, t0)
    float bce = fmaxf(p0, 0.0f) - p0 * t0 + log1pf(__expf(-fabsf(p0)));
    if (noobj) { s0 = bce; s1 = 1.0f; }

    // ---- obj-only (≈5% of lanes): second float4s + box/IoU/obj terms ----
    if (obj) {
        float4 Bv = pa[pi + 1];
        float4 TB = pt[ti + 1];

        float p1 = o==0 ? A.y  : o==1 ? A.z  : o==2 ? A.w  : Bv.x;
        float p2 = o==0 ? A.z  : o==1 ? A.w  : o==2 ? Bv.x : Bv.y;
        float p3 = o==0 ? A.w  : o==1 ? Bv.x : o==2 ? Bv.y : Bv.z;
        float p4 = o==0 ? Bv.x : o==1 ? Bv.y : o==2 ? Bv.z : Bv.w;

        float t1 = oh ? TA.w : TA.y;
        float t2 = oh ? TB.x : TA.z;
        float t3 = oh ? TB.y : TA.w;
        float t4 = oh ? TB.z : TB.x;
        t5       = oh ? TB.w : TB.y;

        // midpoint IoU: b1 = pred[0:4], b2 = target[1:5]
        float b1x1 = p0 - p2 * 0.5f, b1y1 = p1 - p3 * 0.5f;
        float b1x2 = p0 + p2 * 0.5f, b1y2 = p1 + p3 * 0.5f;
        float b2x1 = t1 - t3 * 0.5f, b2y1 = t2 - t4 * 0.5f;
        float b2x2 = t1 + t3 * 0.5f, b2y2 = t2 + t4 * 0.5f;
        float xi1 = fmaxf(b1x1, b2x1), yi1 = fmaxf(b1y1, b2y1);
        float xi2 = fminf(b1x2, b2x2), yi2 = fminf(b1y2, b2y2);
        float inter = fmaxf(xi2 - xi1, 0.0f) * fmaxf(yi2 - yi1, 0.0f);
        float a1 = fabsf((b1x2 - b1x1) * (b1y2 - b1y1));
        float a2 = fabsf((b2x2 - b2x1) * (b2y2 - b2y1));
        float iou = inter / (a1 + a2 - inter + 1e-6f);

        float pobj = 1.0f / (1.0f + __expf(-p0));
        float dob  = pobj - iou;            // t0 == 1 here

        float d1 = 1.0f / (1.0f + __expf(-p1)) - t1;
        float d2 = 1.0f / (1.0f + __expf(-p2)) - t2;
        float d3 = 1.0f / (1.0f + __expf(-p3)) - t3;
        float d4 = 1.0f / (1.0f + __expf(-p4)) - t4;

        s2 = dob * dob;
        s4 = d1*d1 + d2*d2 + d3*d3 + d4*d4;
    }

    // ---- wave-cooperative softmax for obj cells only ----
    unsigned long long mask = __ballot(obj);
    if (lane == 0) s3 = (float)__popcll(mask);          // n_obj for this wave

    const int waveCell0 = blockIdx.x * TPB + wid * 64;
    while (mask) {
        int L = __builtin_ctzll(mask);                  // wave-uniform owner lane
        mask &= mask - 1;

        const float* row = pred + (size_t)(waveCell0 + L) * PS;
        // 80 logits: lanes 0..63 read class=lane, lanes 0..15 also class=64+lane
        float v0 = row[5 + lane];
        float v1 = (lane < 16) ? row[69 + lane] : -INFINITY;

        float m = fmaxf(v0, v1);
        #pragma unroll
        for (int off = 1; off < 64; off <<= 1)
            m = fmaxf(m, __shfl_xor(m, off));

        float e = __expf(v0 - m) + ((lane < 16) ? __expf(v1 - m) : 0.0f);
        #pragma unroll
        for (int off = 1; off < 64; off <<= 1)
            e += __shfl_xor(e, off);

        int lbl = (int)__shfl(t5, L);
        float sel = (lbl < 64) ? __shfl(v0, lbl) : __shfl(v1, lbl - 64);

        if (lane == 0) s5 += __logf(e) - (sel - m);
    }

    // ---- wave butterfly reduction of the 6 partials ----
    #pragma unroll
    for (int off = 1; off < 64; off <<= 1) {
        s0 += __shfl_xor(s0, off);
        s1 += __shfl_xor(s1, off);
        s2 += __shfl_xor(s2, off);
        s3 += __shfl_xor(s3, off);
        s4 += __shfl_xor(s4, off);
        s5 += __shfl_xor(s5, off);
    }

    // ---- cross-wave reduction (4 waves), one float4-pair store per block ----
    if (lane == 0) {
        red[wid][0] = s0; red[wid][1] = s1; red[wid][2] = s2;
        red[wid][3] = s3; red[wid][4] = s4; red[wid][5] = s5;
    }
    __syncthreads();
    if (tid == 0) {
        float a0=0.f,a1=0.f,a2=0.f,a3=0.f,a4=0.f,a5=0.f;
        #pragma unroll
        for (int w = 0; w < 4; ++w) {
            a0 += red[w][0]; a1 += red[w][1]; a2 += red[w][2];
            a3 += red[w][3]; a4 += red[w][4]; a5 += red[w][5];
        }
        float4* slot = (float4*)(part + (size_t)blockIdx.x * 8);
        slot[0] = make_float4(a0, a1, a2, a3);
        slot[1] = make_float4(a4, a5, 0.0f, 0.0f);
    }
}

// Reduction over NBLK partial sets + final loss computation.
__global__ __launch_bounds__(1024) void yolo_reduce(const float* __restrict__ part,
                                                    float* __restrict__ out)
{
    float a0=0.f,a1=0.f,a2=0.f,a3=0.f,a4=0.f,a5=0.f;
    int i = threadIdx.x;
    if (i < NBLK) {
        const float4* slot = (const float4*)(part + (size_t)i * 8);
        float4 v0 = slot[0];
        float4 v1 = slot[1];
        a0 = v0.x; a1 = v0.y; a2 = v0.z; a3 = v0.w; a4 = v1.x; a5 = v1.y;
    }

    #pragma unroll
    for (int off = 32; off > 0; off >>= 1) {
        a0 += __shfl_down(a0, off);
        a1 += __shfl_down(a1, off);
        a2 += __shfl_down(a2, off);
        a3 += __shfl_down(a3, off);
        a4 += __shfl_down(a4, off);
        a5 += __shfl_down(a5, off);
    }

    __shared__ float red[16][6];
    int lane = threadIdx.x & 63;
    int wid  = threadIdx.x >> 6;
    if (lane == 0) {
        red[wid][0] = a0; red[wid][1] = a1; red[wid][2] = a2;
        red[wid][3] = a3; red[wid][4] = a4; red[wid][5] = a5;
    }
    __syncthreads();
    if (threadIdx.x == 0) {
        float b0=0.f,b1=0.f,b2=0.f,b3=0.f,b4=0.f,b5=0.f;
        #pragma unroll
        for (int w = 0; w < 16; ++w) {
            b0 += red[w][0]; b1 += red[w][1]; b2 += red[w][2];
            b3 += red[w][3]; b4 += red[w][4]; b5 += red[w][5];
        }
        float n_noobj = b1;
        float n_obj   = b3;
        // return order: (5*box, 1*object, 0.5*noobj, 1*class)
        out[0] = 5.0f * b4 / fmaxf(n_obj * 4.0f, 1.0f);
        out[1] = 1.0f * b2 / fmaxf(n_obj, 1.0f);
        out[2] = 0.5f * b0 / fmaxf(n_noobj, 1.0f);
        out[3] = 1.0f * b5 / fmaxf(n_obj, 1.0f);
    }
}

extern "C" void kernel_launch(void* const* d_in, const int* in_sizes, int n_in,
                              void* d_out, int out_size, void* d_ws, size_t ws_size,
                              hipStream_t stream)
{
    const float* pred = (const float*)d_in[0];
    const float* tgt  = (const float*)d_in[1];
    float* out  = (float*)d_out;
    float* part = (float*)d_ws;   // needs NBLK*8*4 = 32,448 B

    yolo_main<<<NBLK, TPB, 0, stream>>>(pred, tgt, part);
    yolo_reduce<<<1, 1024, 0, stream>>>(part, out);
}

// Round 12
// 21.174 us; speedup vs baseline: 7.2787x; 1.1134x over previous
//
#include <hip/hip_runtime.h>
#include <math.h>
#include <stdint.h>

// Problem constants (from reference): B=32, A=3, S=52, C=80
constexpr int NCELL = 32 * 3 * 52 * 52;   // 259584 = 256 * 1014
constexpr int PS = 85;                    // prediction channels (5 + C)
constexpr int TPB = 256;
constexpr int NBLK = NCELL / TPB;         // 1014

// d_ws: per-block partials, 8 floats (32 B) per block; NBLK slots.
// [b*8 + 0..5] = {bce_noobj, n_noobj, obj_term, n_obj, box_se, nll}

__global__ __launch_bounds__(TPB) void yolo_main(const float* __restrict__ pred,
                                                 const float* __restrict__ tgt,
                                                 float* __restrict__ part)
{
    const int tid  = threadIdx.x;
    const int wid  = tid >> 6;
    const int lane = tid & 63;
    const int cell = blockIdx.x * TPB + tid;            // one cell per thread
    const int cell0 = blockIdx.x * TPB;                 // block's first cell

    __shared__ float red[4][6];
    __shared__ int   cnt[4];
    __shared__ int   qd[TPB];    // packed obj queue: tid | (label<<8)

    // ---- always: first aligned float4 of the pred window (contains p0) ----
    // 85c mod 4 == c mod 4; window [85c & ~3, +4) always holds dword 85c.
    const int pi = (cell * PS) >> 2;
    const float4* pa = (const float4*)pred;
    float4 A = pa[pi];
    const int o = cell & 3;
    float p0 = o==0 ? A.x : o==1 ? A.y : o==2 ? A.z : A.w;

    // ---- always: first aligned float4 of the tgt window (contains t0) ----
    // 6c mod 4 = 2*(c&1); t0 = TA.x (even c) or TA.z (odd c).
    const int ti = (cell * 6) >> 2;
    const float4* pt = (const float4*)tgt;
    float4 TA = pt[ti];
    const bool oh = (cell & 1);
    float t0 = oh ? TA.z : TA.x;

    const bool obj   = (t0 == 1.0f);
    const bool noobj = (t0 == 0.0f);

    float s0=0.f, s1=0.f, s2=0.f, s3=0.f, s4=0.f, s5=0.f;
    int lbl_self = 0;

    // BCE-with-logits on objectness (uses only p0, t0)
    float bce = fmaxf(p0, 0.0f) - p0 * t0 + log1pf(__expf(-fabsf(p0)));
    if (noobj) { s0 = bce; s1 = 1.0f; }

    // ---- obj-only (≈5% of lanes): second float4s + box/IoU/obj terms ----
    if (obj) {
        float4 Bv = pa[pi + 1];
        float4 TB = pt[ti + 1];

        float p1 = o==0 ? A.y  : o==1 ? A.z  : o==2 ? A.w  : Bv.x;
        float p2 = o==0 ? A.z  : o==1 ? A.w  : o==2 ? Bv.x : Bv.y;
        float p3 = o==0 ? A.w  : o==1 ? Bv.x : o==2 ? Bv.y : Bv.z;
        float p4 = o==0 ? Bv.x : o==1 ? Bv.y : o==2 ? Bv.z : Bv.w;

        float t1 = oh ? TA.w : TA.y;
        float t2 = oh ? TB.x : TA.z;
        float t3 = oh ? TB.y : TA.w;
        float t4 = oh ? TB.z : TB.x;
        float t5 = oh ? TB.w : TB.y;
        lbl_self = (int)t5;

        // midpoint IoU: b1 = pred[0:4], b2 = target[1:5]
        float b1x1 = p0 - p2 * 0.5f, b1y1 = p1 - p3 * 0.5f;
        float b1x2 = p0 + p2 * 0.5f, b1y2 = p1 + p3 * 0.5f;
        float b2x1 = t1 - t3 * 0.5f, b2y1 = t2 - t4 * 0.5f;
        float b2x2 = t1 + t3 * 0.5f, b2y2 = t2 + t4 * 0.5f;
        float xi1 = fmaxf(b1x1, b2x1), yi1 = fmaxf(b1y1, b2y1);
        float xi2 = fminf(b1x2, b2x2), yi2 = fminf(b1y2, b2y2);
        float inter = fmaxf(xi2 - xi1, 0.0f) * fmaxf(yi2 - yi1, 0.0f);
        float a1 = fabsf((b1x2 - b1x1) * (b1y2 - b1y1));
        float a2 = fabsf((b2x2 - b2x1) * (b2y2 - b2y1));
        float iou = inter / (a1 + a2 - inter + 1e-6f);

        float pobj = 1.0f / (1.0f + __expf(-p0));
        float dob  = pobj - iou;            // t0 == 1 here

        float d1 = 1.0f / (1.0f + __expf(-p1)) - t1;
        float d2 = 1.0f / (1.0f + __expf(-p2)) - t2;
        float d3 = 1.0f / (1.0f + __expf(-p3)) - t3;
        float d4 = 1.0f / (1.0f + __expf(-p4)) - t4;

        s2 = dob * dob;
        s4 = d1*d1 + d2*d2 + d3*d3 + d4*d4;
    }

    // ---- build block-level obj queue (ballot + prefix into LDS) ----
    unsigned long long mask = __ballot(obj);
    int mycnt = __popcll(mask);
    if (lane == 0) { s3 = (float)mycnt; cnt[wid] = mycnt; }
    __syncthreads();
    int qoff = 0;
    #pragma unroll
    for (int w = 0; w < 4; ++w) if (w < wid) qoff += cnt[w];
    const int nq = cnt[0] + cnt[1] + cnt[2] + cnt[3];
    if (obj) {
        int rank = __popcll(mask & ((1ull << lane) - 1ull));
        qd[qoff + rank] = tid | (lbl_self << 8);
    }
    __syncthreads();

    // ---- wave-cooperative softmax over the shared queue (round-robin),
    //      depth-1 software prefetch to hide HBM latency ----
    {
        int q = wid;
        float v0 = -INFINITY, v1 = -INFINITY;
        int lbl = 0;
        if (q < nq) {
            int e = qd[q];
            const float* row = pred + (size_t)(cell0 + (e & 255)) * PS;
            lbl = e >> 8;
            v0 = row[5 + lane];
            v1 = (lane < 16) ? row[69 + lane] : -INFINITY;
        }
        while (q < nq) {
            int qn = q + 4;
            float nv0 = -INFINITY, nv1 = -INFINITY;
            int nlbl = 0;
            if (qn < nq) {      // prefetch next item's row (independent loads)
                int e = qd[qn];
                const float* row = pred + (size_t)(cell0 + (e & 255)) * PS;
                nlbl = e >> 8;
                nv0 = row[5 + lane];
                nv1 = (lane < 16) ? row[69 + lane] : -INFINITY;
            }

            // consume current item
            float m = fmaxf(v0, v1);
            #pragma unroll
            for (int off = 1; off < 64; off <<= 1)
                m = fmaxf(m, __shfl_xor(m, off));

            float e = __expf(v0 - m) + ((lane < 16) ? __expf(v1 - m) : 0.0f);
            #pragma unroll
            for (int off = 1; off < 64; off <<= 1)
                e += __shfl_xor(e, off);

            float sel = (lbl < 64) ? __shfl(v0, lbl) : __shfl(v1, lbl - 64);
            if (lane == 0) s5 += __logf(e) - (sel - m);

            v0 = nv0; v1 = nv1; lbl = nlbl;
            q = qn;
        }
    }

    // ---- wave butterfly reduction of the 6 partials ----
    #pragma unroll
    for (int off = 1; off < 64; off <<= 1) {
        s0 += __shfl_xor(s0, off);
        s1 += __shfl_xor(s1, off);
        s2 += __shfl_xor(s2, off);
        s3 += __shfl_xor(s3, off);
        s4 += __shfl_xor(s4, off);
        s5 += __shfl_xor(s5, off);
    }

    // ---- cross-wave reduction (4 waves), one float4-pair store per block ----
    if (lane == 0) {
        red[wid][0] = s0; red[wid][1] = s1; red[wid][2] = s2;
        red[wid][3] = s3; red[wid][4] = s4; red[wid][5] = s5;
    }
    __syncthreads();
    if (tid == 0) {
        float a0=0.f,a1=0.f,a2=0.f,a3=0.f,a4=0.f,a5=0.f;
        #pragma unroll
        for (int w = 0; w < 4; ++w) {
            a0 += red[w][0]; a1 += red[w][1]; a2 += red[w][2];
            a3 += red[w][3]; a4 += red[w][4]; a5 += red[w][5];
        }
        float4* slot = (float4*)(part + (size_t)blockIdx.x * 8);
        slot[0] = make_float4(a0, a1, a2, a3);
        slot[1] = make_float4(a4, a5, 0.0f, 0.0f);
    }
}

// Reduction over NBLK partial sets + final loss computation.
__global__ __launch_bounds__(1024) void yolo_reduce(const float* __restrict__ part,
                                                    float* __restrict__ out)
{
    float a0=0.f,a1=0.f,a2=0.f,a3=0.f,a4=0.f,a5=0.f;
    int i = threadIdx.x;
    if (i < NBLK) {
        const float4* slot = (const float4*)(part + (size_t)i * 8);
        float4 v0 = slot[0];
        float4 v1 = slot[1];
        a0 = v0.x; a1 = v0.y; a2 = v0.z; a3 = v0.w; a4 = v1.x; a5 = v1.y;
    }

    #pragma unroll
    for (int off = 32; off > 0; off >>= 1) {
        a0 += __shfl_down(a0, off);
        a1 += __shfl_down(a1, off);
        a2 += __shfl_down(a2, off);
        a3 += __shfl_down(a3, off);
        a4 += __shfl_down(a4, off);
        a5 += __shfl_down(a5, off);
    }

    __shared__ float red[16][6];
    int lane = threadIdx.x & 63;
    int wid  = threadIdx.x >> 6;
    if (lane == 0) {
        red[wid][0] = a0; red[wid][1] = a1; red[wid][2] = a2;
        red[wid][3] = a3; red[wid][4] = a4; red[wid][5] = a5;
    }
    __syncthreads();
    if (threadIdx.x == 0) {
        float b0=0.f,b1=0.f,b2=0.f,b3=0.f,b4=0.f,b5=0.f;
        #pragma unroll
        for (int w = 0; w < 16; ++w) {
            b0 += red[w][0]; b1 += red[w][1]; b2 += red[w][2];
            b3 += red[w][3]; b4 += red[w][4]; b5 += red[w][5];
        }
        float n_noobj = b1;
        float n_obj   = b3;
        // return order: (5*box, 1*object, 0.5*noobj, 1*class)
        out[0] = 5.0f * b4 / fmaxf(n_obj * 4.0f, 1.0f);
        out[1] = 1.0f * b2 / fmaxf(n_obj, 1.0f);
        out[2] = 0.5f * b0 / fmaxf(n_noobj, 1.0f);
        out[3] = 1.0f * b5 / fmaxf(n_obj, 1.0f);
    }
}

extern "C" void kernel_launch(void* const* d_in, const int* in_sizes, int n_in,
                              void* d_out, int out_size, void* d_ws, size_t ws_size,
                              hipStream_t stream)
{
    const float* pred = (const float*)d_in[0];
    const float* tgt  = (const float*)d_in[1];
    float* out  = (float*)d_out;
    float* part = (float*)d_ws;   // needs NBLK*8*4 = 32,448 B

    yolo_main<<<NBLK, TPB, 0, stream>>>(pred, tgt, part);
    yolo_reduce<<<1, 1024, 0, stream>>>(part, out);
}